// Round 10
// baseline (459.529 us; speedup 1.0000x reference)
//
#include <hip/hip_runtime.h>
#include <hip/hip_bf16.h>

#define N_NODES 100000
#define N_EDGES 1600000
#define F_IN 128
#define F_HID 256
#define F_OUT 128

typedef unsigned short ushort_t;
typedef __attribute__((ext_vector_type(4))) float f32x4;
typedef __attribute__((ext_vector_type(8))) short bf16x8;

#define GAS __attribute__((address_space(1)))
#define LAS __attribute__((address_space(3)))

__device__ __forceinline__ float bf2f(ushort_t u) {
    unsigned int x = ((unsigned int)u) << 16;
    return __builtin_bit_cast(float, x);
}
__device__ __forceinline__ ushort_t f2bf(float f) {
    unsigned int x = __builtin_bit_cast(unsigned int, f);
    unsigned int r = (x + 0x7fffu + ((x >> 16) & 1u)) >> 16;
    return (ushort_t)r;
}

// ---------------- CSR build ----------------
__global__ __launch_bounds__(256) void deg_count_kernel(const int* __restrict__ dst,
                                                        int* __restrict__ cnt, int n) {
    int i = blockIdx.x * 256 + threadIdx.x;
    if (i < n) atomicAdd(&cnt[__builtin_nontemporal_load(dst + i)], 1);
}

__global__ __launch_bounds__(256) void invdeg_kernel(const int* __restrict__ cnt,
                                                     float* __restrict__ inv, int n) {
    int i = blockIdx.x * 256 + threadIdx.x;
    if (i < n) inv[i] = 1.0f / fmaxf((float)cnt[i], 1.0f);
}

__global__ __launch_bounds__(1024) void scan1_kernel(const int* __restrict__ cnt,
                                                     int* __restrict__ rowptr,
                                                     int* __restrict__ blockSums, int n) {
    __shared__ int tmp[1024];
    int tid = threadIdx.x;
    int i = blockIdx.x * 1024 + tid;
    int v = (i < n) ? cnt[i] : 0;
    tmp[tid] = v;
    __syncthreads();
#pragma unroll
    for (int off = 1; off < 1024; off <<= 1) {
        int t = (tid >= off) ? tmp[tid - off] : 0;
        __syncthreads();
        tmp[tid] += t;
        __syncthreads();
    }
    if (i < n) rowptr[i] = tmp[tid] - v;
    if (tid == 1023) blockSums[blockIdx.x] = tmp[1023];
}

__global__ __launch_bounds__(128) void scan2_kernel(int* __restrict__ blockSums, int nb) {
    __shared__ int tmp[128];
    int tid = threadIdx.x;
    int v = (tid < nb) ? blockSums[tid] : 0;
    tmp[tid] = v;
    __syncthreads();
#pragma unroll
    for (int off = 1; off < 128; off <<= 1) {
        int t = (tid >= off) ? tmp[tid - off] : 0;
        __syncthreads();
        tmp[tid] += t;
        __syncthreads();
    }
    if (tid < nb) blockSums[tid] = tmp[tid] - v;
}

__global__ __launch_bounds__(1024) void scan3_kernel(int* __restrict__ rowptr,
                                                     const int* __restrict__ blockSums, int n) {
    int i = blockIdx.x * 1024 + threadIdx.x;
    if (i < n) rowptr[i] = rowptr[i] + blockSums[blockIdx.x];
    if (i == 0) rowptr[n] = N_EDGES;
}

// ---------------- 2-pass bucket sort fill ----------------
#define NBUCK ((N_NODES + 255) >> 8)  // 391
#define CHUNK 4096

__global__ __launch_bounds__(256) void bucket_init_kernel(const int* __restrict__ rowptr,
                                                          int* __restrict__ bcursor) {
    int b = blockIdx.x * 256 + threadIdx.x;
    if (b < NBUCK) bcursor[b] = rowptr[b << 8];
}

__global__ __launch_bounds__(256) void bin_edges_kernel(
    const int* __restrict__ src, const int* __restrict__ dst,
    int* __restrict__ bcursor, unsigned int* __restrict__ pairs, int n) {
    __shared__ int sdst[CHUNK];
    __shared__ int ssrc[CHUNK];
    __shared__ int hist[NBUCK];
    __shared__ int resv[NBUCK];
    int tid = threadIdx.x;
    int e0 = blockIdx.x * CHUNK;
    int cnt = n - e0; if (cnt > CHUNK) cnt = CHUNK;
    for (int b = tid; b < NBUCK; b += 256) hist[b] = 0;
    __syncthreads();
    for (int i = tid; i < cnt; i += 256) {
        int d = __builtin_nontemporal_load(dst + e0 + i);
        int s = __builtin_nontemporal_load(src + e0 + i);
        sdst[i] = d;
        ssrc[i] = s;
        atomicAdd(&hist[d >> 8], 1);
    }
    __syncthreads();
    for (int b = tid; b < NBUCK; b += 256) {
        int h = hist[b];
        resv[b] = h ? atomicAdd(&bcursor[b], h) : 0;
        hist[b] = 0;  // reuse as local offset
    }
    __syncthreads();
    for (int i = tid; i < cnt; i += 256) {
        int d = sdst[i], s = ssrc[i];
        int b = d >> 8;
        int off = atomicAdd(&hist[b], 1);
        pairs[resv[b] + off] = ((unsigned)(d & 255) << 17) | (unsigned)s;
    }
}

__global__ __launch_bounds__(256) void sort_bucket_kernel(
    const unsigned int* __restrict__ pairs, const int* __restrict__ rowptr,
    int* __restrict__ csr_src, int nNodes) {
    __shared__ int lcnt[256];
    __shared__ int lrp[257];
    int tid = threadIdx.x;
    int base = blockIdx.x << 8;
    int nn = nNodes - base; if (nn > 256) nn = 256;
    if (tid < nn) { lrp[tid] = rowptr[base + tid]; lcnt[tid] = 0; }
    if (tid == 0) lrp[nn] = rowptr[base + nn];
    __syncthreads();
    int e0 = lrp[0], e1 = lrp[nn];
    for (int i = e0 + tid; i < e1; i += 256) {
        unsigned v = pairs[i];
        int s = (int)(v & 0x1FFFFu);
        int j = (int)(v >> 17);
        int off = atomicAdd(&lcnt[j], 1);
        csr_src[lrp[j] + off] = s;
    }
}

// ---------------- fp32 -> bf16 converts ----------------
// x (M,128) fp32 -> xb (M,128) bf16 compact
__global__ __launch_bounds__(256) void convert_x_kernel(const float* __restrict__ x,
                                                        ushort_t* __restrict__ xb, int n4) {
    int i = blockIdx.x * 256 + threadIdx.x;
    if (i >= n4) return;
    int e = i * 4;
    f32x4 v = __builtin_nontemporal_load((const f32x4*)(x + e));
    ushort4 o;
    o.x = f2bf(v.x); o.y = f2bf(v.y); o.z = f2bf(v.z); o.w = f2bf(v.w);
    *(ushort4*)(xb + e) = o;
}

// Wt[n][k] = bf16( k<Kx ? W1[k][n] : W2[k-Kx][n] )  -- stack along K
__global__ __launch_bounds__(256) void wtransK_kernel(const float* __restrict__ W1,
                                                      const float* __restrict__ W2,
                                                      ushort_t* __restrict__ Wt,
                                                      int Kx, int Ktot, int N) {
    int i = blockIdx.x * 256 + threadIdx.x;
    if (i >= N * Ktot) return;
    int n = i / Ktot, k = i - n * Ktot;
    float v = (k < Kx) ? W1[(size_t)k * N + n] : W2[(size_t)(k - Kx) * N + n];
    Wt[(size_t)n * Ktot + k] = f2bf(v);
}

// Wt[n][k]: n<Nh -> Wa[k][n], else Wb[k][n-Nh]  -- stack along N
__global__ __launch_bounds__(256) void wtransN_kernel(const float* __restrict__ Wa,
                                                      const float* __restrict__ Wb,
                                                      ushort_t* __restrict__ Wt,
                                                      int K, int Nh) {
    int i = blockIdx.x * 256 + threadIdx.x;
    if (i >= 2 * Nh * K) return;
    int n = i / K, k = i - n * K;
    const float* W = (n < Nh) ? Wa : Wb;
    int nn = (n < Nh) ? n : n - Nh;
    Wt[(size_t)n * K + k] = f2bf(W[(size_t)k * Nh + nn]);
}

// ---------------- 16-lane-per-edge gather (layer-2 final) ----------------
#define ACC8(v)                                                     \
    acc[0] += bf2f((ushort_t)((v).x & 0xffffu));                    \
    acc[1] += bf2f((ushort_t)((v).x >> 16));                        \
    acc[2] += bf2f((ushort_t)((v).y & 0xffffu));                    \
    acc[3] += bf2f((ushort_t)((v).y >> 16));                        \
    acc[4] += bf2f((ushort_t)((v).z & 0xffffu));                    \
    acc[5] += bf2f((ushort_t)((v).z >> 16));                        \
    acc[6] += bf2f((ushort_t)((v).w & 0xffffu));                    \
    acc[7] += bf2f((ushort_t)((v).w >> 16));

__global__ __launch_bounds__(256) void gather_final_kernel(
    const ushort_t* __restrict__ H, int ldh,
    const int* __restrict__ rowptr, const int* __restrict__ csr_src,
    const float* __restrict__ invdeg,
    const ushort_t* __restrict__ uself, int ldu,
    const float* __restrict__ bias,
    float* __restrict__ outp, int ldo, int nNodes) {
    int lane = threadIdx.x & 63;
    int node = blockIdx.x * 4 + (threadIdx.x >> 6);
    if (node >= nNodes) return;
    int grp = lane >> 4, sub = lane & 15;
    int start = rowptr[node], end = rowptr[node + 1];
    const size_t cofs = (size_t)sub * 8;
    float acc[8] = {};
    for (int e = start + grp; e < end; e += 16) {
        int s0 = csr_src[e];
        uint4 v0 = *(const uint4*)(H + (size_t)s0 * ldh + cofs);
        bool p1 = (e + 4) < end;
        int s1 = p1 ? csr_src[e + 4] : s0;
        uint4 v1 = *(const uint4*)(H + (size_t)s1 * ldh + cofs);
        bool p2 = (e + 8) < end;
        int s2 = p2 ? csr_src[e + 8] : s0;
        uint4 v2 = *(const uint4*)(H + (size_t)s2 * ldh + cofs);
        bool p3 = (e + 12) < end;
        int s3 = p3 ? csr_src[e + 12] : s0;
        uint4 v3 = *(const uint4*)(H + (size_t)s3 * ldh + cofs);
        ACC8(v0);
        if (p1) { ACC8(v1); }
        if (p2) { ACC8(v2); }
        if (p3) { ACC8(v3); }
    }
#pragma unroll
    for (int j = 0; j < 8; ++j) {
        acc[j] += __shfl_xor(acc[j], 16);
        acc[j] += __shfl_xor(acc[j], 32);
    }
    if (grp == 0) {
        float sc = invdeg[node];
        uint4 us = *(const uint4*)(uself + (size_t)node * ldu + cofs);
        f32x4 o0, o1;
        o0.x = acc[0] * sc + bf2f((ushort_t)(us.x & 0xffffu)) + bias[cofs + 0];
        o0.y = acc[1] * sc + bf2f((ushort_t)(us.x >> 16)) + bias[cofs + 1];
        o0.z = acc[2] * sc + bf2f((ushort_t)(us.y & 0xffffu)) + bias[cofs + 2];
        o0.w = acc[3] * sc + bf2f((ushort_t)(us.y >> 16)) + bias[cofs + 3];
        o1.x = acc[4] * sc + bf2f((ushort_t)(us.z & 0xffffu)) + bias[cofs + 4];
        o1.y = acc[5] * sc + bf2f((ushort_t)(us.z >> 16)) + bias[cofs + 5];
        o1.z = acc[6] * sc + bf2f((ushort_t)(us.w & 0xffffu)) + bias[cofs + 6];
        o1.w = acc[7] * sc + bf2f((ushort_t)(us.w >> 16)) + bias[cofs + 7];
        float* op = outp + (size_t)node * ldo + cofs;
        __builtin_nontemporal_store(o0, (f32x4*)op);
        __builtin_nontemporal_store(o1, (f32x4*)(op + 4));
    }
}

// ---------------- 512-thread full-N bf16 MFMA GEMM, optional fused gather ----
// C[M][256] = A'[M][256] @ Bt[256][256]^T; 8 waves = 2x4 grid of 64x64 tiles.
// FUSE=1: A' = [A(xb,128 cols) | Agg(LDS, gathered neighbor-mean of xb)]
// FUSE=0: A' = A (lda=256)
// MODE 0: bf16 out + bias + sigmoid ; MODE 1: bf16 out
template <int FUSE, int MODE>
__global__ __launch_bounds__(512) void gemm_mfma512_kernel(
    const ushort_t* __restrict__ A, int lda,
    const ushort_t* __restrict__ Bt,
    const float* __restrict__ bias,
    const int* __restrict__ rowptr, const int* __restrict__ csr_src,
    const float* __restrict__ invdeg,
    ushort_t* __restrict__ Cout, int M) {
    constexpr int NN = 256, KK = 256;
    __shared__ ushort_t shmem[128 * 64 + 256 * 64];  // As | Bs
    __shared__ ushort_t Agg[FUSE ? 128 * 128 : 8];
    ushort_t* As = shmem;
    ushort_t* Bs = shmem + 128 * 64;
    int tid = threadIdx.x;
    int lane = tid & 63, wid = tid >> 6;
    int l15 = lane & 15, kgrp = lane >> 4, l7 = lane & 7, l8 = lane >> 3;
    int bm = blockIdx.x * 128;
    int wr = (wid >> 2) * 64, wc = (wid & 3) * 64;

    if constexpr (FUSE) {
        // gather neighbor-mean for rows bm..bm+127 into Agg (swizzled bf16).
        int grp = lane >> 4, sub = lane & 15;
        const size_t cofs = (size_t)sub * 8;
        for (int ni = 0; ni < 16; ++ni) {
            int node = bm + wid * 16 + ni;
            if (node >= M) break;
            int start = rowptr[node], end = rowptr[node + 1];
            float acc[8] = {};
            for (int e = start + grp; e < end; e += 16) {
                int s0 = csr_src[e];
                uint4 v0 = *(const uint4*)(A + (size_t)s0 * lda + cofs);
                bool p1 = (e + 4) < end;
                int s1 = p1 ? csr_src[e + 4] : s0;
                uint4 v1 = *(const uint4*)(A + (size_t)s1 * lda + cofs);
                bool p2 = (e + 8) < end;
                int s2 = p2 ? csr_src[e + 8] : s0;
                uint4 v2 = *(const uint4*)(A + (size_t)s2 * lda + cofs);
                bool p3 = (e + 12) < end;
                int s3 = p3 ? csr_src[e + 12] : s0;
                uint4 v3 = *(const uint4*)(A + (size_t)s3 * lda + cofs);
                ACC8(v0);
                if (p1) { ACC8(v1); }
                if (p2) { ACC8(v2); }
                if (p3) { ACC8(v3); }
            }
#pragma unroll
            for (int j = 0; j < 8; ++j) {
                acc[j] += __shfl_xor(acc[j], 16);
                acc[j] += __shfl_xor(acc[j], 32);
            }
            if (grp == 0) {
                float sc = invdeg[node];
                int r = wid * 16 + ni;
                int c0 = sub * 8;
                int pos = (c0 & 63) ^ ((r & 7) << 3);
                bf16x8 pk;
#pragma unroll
                for (int j = 0; j < 8; ++j) pk[j] = (short)f2bf(acc[j] * sc);
                *(bf16x8*)(&Agg[r * 128 + (c0 >> 6) * 64 + pos]) = pk;
            }
        }
        __syncthreads();
    }

    f32x4 acc[4][4] = {};

    for (int t = 0; t < 4; ++t) {
        int k0 = t * 64;
        if (!FUSE || t < 2) {
#pragma unroll
            for (int tt = 0; tt < 2; ++tt) {
                int c = wid * 2 + tt;
                int row = c * 8 + l8;
                int scol = (l7 ^ (row & 7)) << 3;
                int ar = bm + row; if (ar > M - 1) ar = M - 1;
                __builtin_amdgcn_global_load_lds(
                    (const GAS void*)(A + (size_t)ar * lda + k0 + scol),
                    (LAS void*)(&As[c * 512]), 16, 0, 0);
            }
        }
#pragma unroll
        for (int tt = 0; tt < 4; ++tt) {
            int c = wid * 4 + tt;
            int row = c * 8 + l8;  // 0..255
            int scol = (l7 ^ (row & 7)) << 3;
            __builtin_amdgcn_global_load_lds(
                (const GAS void*)(Bt + (size_t)row * KK + k0 + scol),
                (LAS void*)(&Bs[c * 512]), 16, 0, 0);
        }
        __syncthreads();
#pragma unroll
        for (int kk = 0; kk < 2; ++kk) {
            bf16x8 af[4], bfv[4];
#pragma unroll
            for (int mi = 0; mi < 4; ++mi) {
                int row = wr + mi * 16 + l15;
                if (FUSE && t >= 2) {
                    int ce = (k0 - 128) + kk * 32 + kgrp * 8;
                    int pos = (ce & 63) ^ ((row & 7) << 3);
                    af[mi] = *(const bf16x8*)(&Agg[row * 128 + (ce >> 6) * 64 + pos]);
                } else {
                    int kel = (kk * 32 + kgrp * 8) ^ ((row & 7) << 3);
                    af[mi] = *(const bf16x8*)(&As[row * 64 + kel]);
                }
            }
#pragma unroll
            for (int ni = 0; ni < 4; ++ni) {
                int row = wc + ni * 16 + l15;
                int kel = (kk * 32 + kgrp * 8) ^ ((row & 7) << 3);
                bfv[ni] = *(const bf16x8*)(&Bs[row * 64 + kel]);
            }
#pragma unroll
            for (int mi = 0; mi < 4; ++mi)
#pragma unroll
                for (int ni = 0; ni < 4; ++ni)
                    acc[mi][ni] = __builtin_amdgcn_mfma_f32_16x16x32_bf16(
                        af[mi], bfv[ni], acc[mi][ni], 0, 0, 0);
        }
        __syncthreads();
    }

    // ---- epilogue: per-wave 16x64 slab transpose (wave-private, no barriers) ----
    ushort_t* my = shmem + wid * 1024;
#pragma unroll
    for (int mi = 0; mi < 4; ++mi) {
#pragma unroll
        for (int ni = 0; ni < 4; ++ni) {
            int gcol = wc + ni * 16 + l15;
#pragma unroll
            for (int r = 0; r < 4; ++r) {
                float v = acc[mi][ni][r];
                if (MODE == 0) {
                    v += bias[gcol];
                    v = 1.0f / (1.0f + __expf(-v));
                }
                int lr = kgrp * 4 + r;
                int lc = (ni * 16 + l15) ^ (kgrp << 3);
                my[lr * 64 + lc] = f2bf(v);
            }
        }
#pragma unroll
        for (int it = 0; it < 2; ++it) {
            int r2 = (lane >> 3) + it * 8;
            int swz = ((r2 >> 2) & 3) << 3;
            int c2 = ((lane & 7) << 3) ^ swz;
            bf16x8 vv = *(const bf16x8*)(&my[r2 * 64 + c2]);
            int grow = bm + wr + mi * 16 + r2;
            if (grow < M) {
                int gc = wc + (c2 ^ swz);
                *(bf16x8*)(&Cout[(size_t)grow * NN + gc]) = vv;
            }
        }
    }
}

extern "C" void kernel_launch(void* const* d_in, const int* in_sizes, int n_in,
                              void* d_out, int out_size, void* d_ws, size_t ws_size,
                              hipStream_t stream) {
    const float* x        = (const float*)d_in[0];
    const int*   src      = (const int*)d_in[1];
    const int*   dst      = (const int*)d_in[2];
    const float* W_self1  = (const float*)d_in[3];
    const float* W_neigh1 = (const float*)d_in[4];
    const float* b1       = (const float*)d_in[5];
    const float* W_self2  = (const float*)d_in[6];
    const float* W_neigh2 = (const float*)d_in[7];
    const float* b2       = (const float*)d_in[8];
    float* out = (float*)d_out;

    // ---- workspace layout ----
    char* p = (char*)d_ws;
    auto alloc = [&](size_t bytes) { char* r = p; p += (bytes + 255) & ~(size_t)255; return r; };
    float*    invdeg   = (float*)alloc((size_t)N_NODES * 4);
    ushort_t* xb       = (ushort_t*)alloc((size_t)N_NODES * 128 * 2);
    ushort_t* h        = (ushort_t*)alloc((size_t)N_NODES * 256 * 2);
    ushort_t* u        = (ushort_t*)alloc((size_t)N_NODES * 256 * 2);  // [u_self | u_neigh]
    ushort_t* Wt1      = (ushort_t*)alloc((size_t)256 * 256 * 2);
    ushort_t* Wt2      = (ushort_t*)alloc((size_t)256 * 256 * 2);
    int* rowptr        = (int*)alloc((size_t)(N_NODES + 1) * 4);
    int* cnt           = (int*)alloc((size_t)N_NODES * 4);
    int* blockSums     = (int*)alloc(1024);
    int* bcursor       = (int*)alloc((size_t)NBUCK * 4);
    unsigned int* pairs= (unsigned int*)alloc((size_t)N_EDGES * 4);
    int* csr_src       = (int*)alloc((size_t)N_EDGES * 4);

    const int SCAN_NB = (N_NODES + 1023) / 1024;

    // ---- converts ----
    convert_x_kernel<<<(N_NODES * F_IN / 4 + 255) / 256, 256, 0, stream>>>(
        x, xb, N_NODES * F_IN / 4);
    wtransK_kernel<<<(256 * 256 + 255) / 256, 256, 0, stream>>>(
        W_self1, W_neigh1, Wt1, 128, 256, 256);
    wtransN_kernel<<<(256 * 256 + 255) / 256, 256, 0, stream>>>(
        W_self2, W_neigh2, Wt2, 256, 128);

    // ---- CSR build: deg -> scan -> bucket-binned sort ----
    hipMemsetAsync(cnt, 0, (size_t)N_NODES * sizeof(int), stream);
    deg_count_kernel<<<(N_EDGES + 255) / 256, 256, 0, stream>>>(dst, cnt, N_EDGES);
    invdeg_kernel<<<(N_NODES + 255) / 256, 256, 0, stream>>>(cnt, invdeg, N_NODES);
    scan1_kernel<<<SCAN_NB, 1024, 0, stream>>>(cnt, rowptr, blockSums, N_NODES);
    scan2_kernel<<<1, 128, 0, stream>>>(blockSums, SCAN_NB);
    scan3_kernel<<<SCAN_NB, 1024, 0, stream>>>(rowptr, blockSums, N_NODES);
    bucket_init_kernel<<<(NBUCK + 255) / 256, 256, 0, stream>>>(rowptr, bcursor);
    bin_edges_kernel<<<(N_EDGES + CHUNK - 1) / CHUNK, 256, 0, stream>>>(
        src, dst, bcursor, pairs, N_EDGES);
    sort_bucket_kernel<<<NBUCK, 256, 0, stream>>>(pairs, rowptr, csr_src, N_NODES);

    // ---- layer 1 (fused gather+GEMM): h = sigmoid([xb|agg] @ Wt1 + b1) ----
    {
        dim3 grid((N_NODES + 127) / 128);
        gemm_mfma512_kernel<1, 0><<<grid, 512, 0, stream>>>(
            xb, 128, Wt1, b1, rowptr, csr_src, invdeg, h, N_NODES);
    }
    // ---- layer 2: u = h @ [Ws2|Wn2] ----
    {
        dim3 grid((N_NODES + 127) / 128);
        gemm_mfma512_kernel<0, 1><<<grid, 512, 0, stream>>>(
            h, 256, Wt2, nullptr, nullptr, nullptr, nullptr, u, N_NODES);
    }
    // ---- out = u_self + b2 + invdeg * gather(u_neigh) ----
    gather_final_kernel<<<(N_NODES + 3) / 4, 256, 0, stream>>>(
        u + 128, 256, rowptr, csr_src, invdeg, u, 256, b2, out, 128, N_NODES);
}

// Round 11
// 308.261 us; speedup vs baseline: 1.4907x; 1.4907x over previous
//
#include <hip/hip_runtime.h>
#include <hip/hip_bf16.h>

#define N_NODES 100000
#define N_EDGES 1600000
#define F_IN 128
#define F_HID 256
#define F_OUT 128

typedef unsigned short ushort_t;
typedef __attribute__((ext_vector_type(4))) float f32x4;
typedef __attribute__((ext_vector_type(8))) short bf16x8;

#define GAS __attribute__((address_space(1)))
#define LAS __attribute__((address_space(3)))

__device__ __forceinline__ float bf2f(ushort_t u) {
    unsigned int x = ((unsigned int)u) << 16;
    return __builtin_bit_cast(float, x);
}
__device__ __forceinline__ ushort_t f2bf(float f) {
    unsigned int x = __builtin_bit_cast(unsigned int, f);
    unsigned int r = (x + 0x7fffu + ((x >> 16) & 1u)) >> 16;
    return (ushort_t)r;
}

// ---------------- bucket-sort CSR build ----------------
// Buckets = 256 consecutive dst nodes. bucket_count -> bucket_scan ->
// bin_edges (packed (j,src) into bucket regions) -> sort_bucket (also
// produces rowptr + invdeg from its LDS counts; no global per-node
// atomic counting pass needed).
#define NBUCK ((N_NODES + 255) >> 8)  // 391
#define CHUNK 4096

__global__ __launch_bounds__(256) void bucket_count_kernel(
    const int* __restrict__ dst, int* __restrict__ bucket_cnt, int n) {
    __shared__ int hist[NBUCK];
    int tid = threadIdx.x;
    int e0 = blockIdx.x * CHUNK;
    int cnt = n - e0; if (cnt > CHUNK) cnt = CHUNK;
    for (int b = tid; b < NBUCK; b += 256) hist[b] = 0;
    __syncthreads();
    for (int i = tid; i < cnt; i += 256) {
        int d = __builtin_nontemporal_load(dst + e0 + i);
        atomicAdd(&hist[d >> 8], 1);
    }
    __syncthreads();
    for (int b = tid; b < NBUCK; b += 256)
        if (hist[b]) atomicAdd(&bucket_cnt[b], hist[b]);
}

// single block: exclusive scan of 391 bucket counts -> bbase, bcursor
__global__ __launch_bounds__(512) void bucket_scan_kernel(
    const int* __restrict__ bucket_cnt, int* __restrict__ bbase,
    int* __restrict__ bcursor, int* __restrict__ rowptr) {
    __shared__ int tmp[512];
    int tid = threadIdx.x;
    int v = (tid < NBUCK) ? bucket_cnt[tid] : 0;
    tmp[tid] = v;
    __syncthreads();
#pragma unroll
    for (int off = 1; off < 512; off <<= 1) {
        int t = (tid >= off) ? tmp[tid - off] : 0;
        __syncthreads();
        tmp[tid] += t;
        __syncthreads();
    }
    if (tid < NBUCK) {
        int base = tmp[tid] - v;  // exclusive
        bbase[tid] = base;
        bcursor[tid] = base;
    }
    if (tid == 0) {
        bbase[NBUCK] = N_EDGES;
        rowptr[N_NODES] = N_EDGES;
    }
}

__global__ __launch_bounds__(256) void bin_edges_kernel(
    const int* __restrict__ src, const int* __restrict__ dst,
    int* __restrict__ bcursor, unsigned int* __restrict__ pairs, int n) {
    __shared__ int sdst[CHUNK];
    __shared__ int ssrc[CHUNK];
    __shared__ int hist[NBUCK];
    __shared__ int resv[NBUCK];
    int tid = threadIdx.x;
    int e0 = blockIdx.x * CHUNK;
    int cnt = n - e0; if (cnt > CHUNK) cnt = CHUNK;
    for (int b = tid; b < NBUCK; b += 256) hist[b] = 0;
    __syncthreads();
    for (int i = tid; i < cnt; i += 256) {
        int d = __builtin_nontemporal_load(dst + e0 + i);
        int s = __builtin_nontemporal_load(src + e0 + i);
        sdst[i] = d;
        ssrc[i] = s;
        atomicAdd(&hist[d >> 8], 1);
    }
    __syncthreads();
    for (int b = tid; b < NBUCK; b += 256) {
        int h = hist[b];
        resv[b] = h ? atomicAdd(&bcursor[b], h) : 0;
        hist[b] = 0;  // reuse as local offset
    }
    __syncthreads();
    for (int i = tid; i < cnt; i += 256) {
        int d = sdst[i], s = ssrc[i];
        int b = d >> 8;
        int off = atomicAdd(&hist[b], 1);
        pairs[resv[b] + off] = ((unsigned)(d & 255) << 17) | (unsigned)s;
    }
}

// per bucket: count -> local scan -> rowptr/invdeg -> place csr_src
__global__ __launch_bounds__(256) void sort_bucket_kernel(
    const unsigned int* __restrict__ pairs, const int* __restrict__ bbase,
    int* __restrict__ rowptr, float* __restrict__ invdeg,
    int* __restrict__ csr_src, int nNodes) {
    __shared__ int lcnt[256];
    __shared__ int lrp[256];
    int tid = threadIdx.x;
    int base = blockIdx.x << 8;
    int nn = nNodes - base; if (nn > 256) nn = 256;
    lcnt[tid] = 0;
    __syncthreads();
    int e0 = bbase[blockIdx.x], e1 = bbase[blockIdx.x + 1];
    for (int i = e0 + tid; i < e1; i += 256)
        atomicAdd(&lcnt[pairs[i] >> 17], 1);
    __syncthreads();
    int v = lcnt[tid];
    lrp[tid] = v;
    __syncthreads();
#pragma unroll
    for (int off = 1; off < 256; off <<= 1) {
        int t = (tid >= off) ? lrp[tid - off] : 0;
        __syncthreads();
        lrp[tid] += t;
        __syncthreads();
    }
    // exclusive global start for node j in lrp[j]; reset lcnt for rank pass
    lcnt[tid] = 0;
    lrp[tid] = lrp[tid] - v + e0;
    if (tid < nn) {
        rowptr[base + tid] = lrp[tid];
        invdeg[base + tid] = 1.0f / fmaxf((float)v, 1.0f);
    }
    __syncthreads();
    for (int i = e0 + tid; i < e1; i += 256) {
        unsigned pv = pairs[i];
        int j = (int)(pv >> 17);
        int off = atomicAdd(&lcnt[j], 1);
        csr_src[lrp[j] + off] = (int)(pv & 0x1FFFFu);
    }
}

// ---------------- fp32 -> bf16 converts ----------------
// x (N,128) fp32 -> A1[:, 0:128] bf16 (A1 row stride 256)
__global__ __launch_bounds__(256) void convert_x_kernel(const float* __restrict__ x,
                                                        ushort_t* __restrict__ A1, int n4) {
    int i = blockIdx.x * 256 + threadIdx.x;
    if (i >= n4) return;
    int e = i * 4;
    int row = e >> 7;
    int col = e & 127;
    f32x4 v = __builtin_nontemporal_load((const f32x4*)(x + (size_t)row * F_IN + col));
    ushort4 o;
    o.x = f2bf(v.x); o.y = f2bf(v.y); o.z = f2bf(v.z); o.w = f2bf(v.w);
    *(ushort4*)(A1 + (size_t)row * 256 + col) = o;
}

// Wt[n][k] = bf16( k<Kx ? W1[k][n] : W2[k-Kx][n] )  -- stack along K
__global__ __launch_bounds__(256) void wtransK_kernel(const float* __restrict__ W1,
                                                      const float* __restrict__ W2,
                                                      ushort_t* __restrict__ Wt,
                                                      int Kx, int Ktot, int N) {
    int i = blockIdx.x * 256 + threadIdx.x;
    if (i >= N * Ktot) return;
    int n = i / Ktot, k = i - n * Ktot;
    float v = (k < Kx) ? W1[(size_t)k * N + n] : W2[(size_t)(k - Kx) * N + n];
    Wt[(size_t)n * Ktot + k] = f2bf(v);
}

// Wt[n][k]: n<Nh -> Wa[k][n], else Wb[k][n-Nh]  -- stack along N
__global__ __launch_bounds__(256) void wtransN_kernel(const float* __restrict__ Wa,
                                                      const float* __restrict__ Wb,
                                                      ushort_t* __restrict__ Wt,
                                                      int K, int Nh) {
    int i = blockIdx.x * 256 + threadIdx.x;
    if (i >= 2 * Nh * K) return;
    int n = i / K, k = i - n * K;
    const float* W = (n < Nh) ? Wa : Wb;
    int nn = (n < Nh) ? n : n - Nh;
    Wt[(size_t)n * K + k] = f2bf(W[(size_t)k * Nh + nn]);
}

// ---------------- 16-lane-per-edge gather, 4 edges per group-iter ----------------
#define ACC8(v)                                                     \
    acc[0] += bf2f((ushort_t)((v).x & 0xffffu));                    \
    acc[1] += bf2f((ushort_t)((v).x >> 16));                        \
    acc[2] += bf2f((ushort_t)((v).y & 0xffffu));                    \
    acc[3] += bf2f((ushort_t)((v).y >> 16));                        \
    acc[4] += bf2f((ushort_t)((v).z & 0xffffu));                    \
    acc[5] += bf2f((ushort_t)((v).z >> 16));                        \
    acc[6] += bf2f((ushort_t)((v).w & 0xffffu));                    \
    acc[7] += bf2f((ushort_t)((v).w >> 16));

template <int MODE>
__global__ __launch_bounds__(256) void gather16_kernel(
    const ushort_t* __restrict__ H, int ldh,
    const int* __restrict__ rowptr, const int* __restrict__ csr_src,
    const float* __restrict__ invdeg,
    const ushort_t* __restrict__ uself, int ldu,
    const float* __restrict__ bias,
    void* __restrict__ outp, int ldo, int nNodes) {
    int lane = threadIdx.x & 63;
    int node = blockIdx.x * 4 + (threadIdx.x >> 6);
    if (node >= nNodes) return;
    int grp = lane >> 4, sub = lane & 15;
    int start = rowptr[node], end = rowptr[node + 1];
    const size_t cofs = (size_t)sub * 8;
    float acc[8] = {};
    for (int e = start + grp; e < end; e += 16) {
        int s0 = csr_src[e];
        uint4 v0 = *(const uint4*)(H + (size_t)s0 * ldh + cofs);
        bool p1 = (e + 4) < end;
        int s1 = p1 ? csr_src[e + 4] : s0;
        uint4 v1 = *(const uint4*)(H + (size_t)s1 * ldh + cofs);
        bool p2 = (e + 8) < end;
        int s2 = p2 ? csr_src[e + 8] : s0;
        uint4 v2 = *(const uint4*)(H + (size_t)s2 * ldh + cofs);
        bool p3 = (e + 12) < end;
        int s3 = p3 ? csr_src[e + 12] : s0;
        uint4 v3 = *(const uint4*)(H + (size_t)s3 * ldh + cofs);
        ACC8(v0);
        if (p1) { ACC8(v1); }
        if (p2) { ACC8(v2); }
        if (p3) { ACC8(v3); }
    }
#pragma unroll
    for (int j = 0; j < 8; ++j) {
        acc[j] += __shfl_xor(acc[j], 16);
        acc[j] += __shfl_xor(acc[j], 32);
    }
    if (grp == 0) {
        float sc = invdeg[node];
        if (MODE == 0) {
            uint4 o;
            o.x = (unsigned)f2bf(acc[0] * sc) | ((unsigned)f2bf(acc[1] * sc) << 16);
            o.y = (unsigned)f2bf(acc[2] * sc) | ((unsigned)f2bf(acc[3] * sc) << 16);
            o.z = (unsigned)f2bf(acc[4] * sc) | ((unsigned)f2bf(acc[5] * sc) << 16);
            o.w = (unsigned)f2bf(acc[6] * sc) | ((unsigned)f2bf(acc[7] * sc) << 16);
            *(uint4*)((ushort_t*)outp + (size_t)node * ldo + cofs) = o;
        } else {
            uint4 us = *(const uint4*)(uself + (size_t)node * ldu + cofs);
            f32x4 o0, o1;
            o0.x = acc[0] * sc + bf2f((ushort_t)(us.x & 0xffffu)) + bias[cofs + 0];
            o0.y = acc[1] * sc + bf2f((ushort_t)(us.x >> 16)) + bias[cofs + 1];
            o0.z = acc[2] * sc + bf2f((ushort_t)(us.y & 0xffffu)) + bias[cofs + 2];
            o0.w = acc[3] * sc + bf2f((ushort_t)(us.y >> 16)) + bias[cofs + 3];
            o1.x = acc[4] * sc + bf2f((ushort_t)(us.z & 0xffffu)) + bias[cofs + 4];
            o1.y = acc[5] * sc + bf2f((ushort_t)(us.z >> 16)) + bias[cofs + 5];
            o1.z = acc[6] * sc + bf2f((ushort_t)(us.w & 0xffffu)) + bias[cofs + 6];
            o1.w = acc[7] * sc + bf2f((ushort_t)(us.w >> 16)) + bias[cofs + 7];
            float* op = (float*)outp + (size_t)node * ldo + cofs;
            __builtin_nontemporal_store(o0, (f32x4*)op);
            __builtin_nontemporal_store(o1, (f32x4*)(op + 4));
        }
    }
}

// ---------------- bf16 MFMA GEMM ----------------
// C = A[M][K] @ Bt[N][K]^T ; 128x128 tile, 4 waves x (64x64), BK=64.
// mode 0: bf16 out, +bias, sigmoid ; mode 1: bf16 out
// Epilogue: per-wave LDS transpose (XOR-swizzled) -> b128 stores.
__global__ __launch_bounds__(256) void gemm_mfma_kernel(
    const ushort_t* __restrict__ A,
    const ushort_t* __restrict__ Bt,
    const float* __restrict__ bias,
    ushort_t* __restrict__ Cout,
    int M, int N, int K, int mode) {
    __shared__ ushort_t shmem[2 * 128 * 64];  // staging As|Bs; reused by epilogue
    ushort_t* As = shmem;
    ushort_t* Bs = shmem + 128 * 64;
    int tid = threadIdx.x;
    int lane = tid & 63, wid = tid >> 6;
    int l15 = lane & 15, kgrp = lane >> 4, l7 = lane & 7, l8 = lane >> 3;
    int bm = blockIdx.x * 128, bn = blockIdx.y * 128;
    int wr = (wid >> 1) * 64, wc = (wid & 1) * 64;

    f32x4 acc[4][4] = {};

    for (int k0 = 0; k0 < K; k0 += 64) {
#pragma unroll
        for (int t = 0; t < 4; ++t) {
            int c = wid * 4 + t;
            int row = c * 8 + l8;
            int scol = ((l7 ^ (row & 7)) << 3);
            int ar = bm + row; if (ar > M - 1) ar = M - 1;
            __builtin_amdgcn_global_load_lds(
                (const GAS void*)(A + (size_t)ar * K + k0 + scol),
                (LAS void*)(&As[c * 512]), 16, 0, 0);
            int br = bn + row;
            __builtin_amdgcn_global_load_lds(
                (const GAS void*)(Bt + (size_t)br * K + k0 + scol),
                (LAS void*)(&Bs[c * 512]), 16, 0, 0);
        }
        __syncthreads();
#pragma unroll
        for (int kk = 0; kk < 2; ++kk) {
            bf16x8 af[4], bfv[4];
#pragma unroll
            for (int mi = 0; mi < 4; ++mi) {
                int row = wr + mi * 16 + l15;
                int kel = (kk * 32 + kgrp * 8) ^ ((row & 7) << 3);
                af[mi] = *(const bf16x8*)(&As[row * 64 + kel]);
            }
#pragma unroll
            for (int ni = 0; ni < 4; ++ni) {
                int row = wc + ni * 16 + l15;
                int kel = (kk * 32 + kgrp * 8) ^ ((row & 7) << 3);
                bfv[ni] = *(const bf16x8*)(&Bs[row * 64 + kel]);
            }
#pragma unroll
            for (int mi = 0; mi < 4; ++mi)
#pragma unroll
                for (int ni = 0; ni < 4; ++ni)
                    acc[mi][ni] = __builtin_amdgcn_mfma_f32_16x16x32_bf16(
                        af[mi], bfv[ni], acc[mi][ni], 0, 0, 0);
        }
        __syncthreads();
    }

    // ---- epilogue: wave-local 64x64 transpose in LDS, then 16B stores ----
    ushort_t* my = shmem + wid * 4096;
#pragma unroll
    for (int mi = 0; mi < 4; ++mi) {
#pragma unroll
        for (int ni = 0; ni < 4; ++ni) {
            int gcol = bn + wc + ni * 16 + l15;
#pragma unroll
            for (int r = 0; r < 4; ++r) {
                float v = acc[mi][ni][r];
                if (mode == 0) {
                    v += bias[gcol];
                    v = 1.0f / (1.0f + __expf(-v));
                }
                int lr = mi * 16 + kgrp * 4 + r;
                int lc = (ni * 16 + l15) ^ (kgrp << 3);
                my[lr * 64 + lc] = f2bf(v);
            }
        }
    }
#pragma unroll
    for (int it = 0; it < 8; ++it) {
        int r2 = (lane >> 3) + it * 8;
        int c2 = ((lane & 7) << 3) ^ (((r2 >> 2) & 3) << 3);
        bf16x8 vv = *(const bf16x8*)(&my[r2 * 64 + c2]);
        int grow = bm + wr + r2;
        if (grow < M) {
            int gc = bn + wc + (c2 ^ (((r2 >> 2) & 3) << 3));
            *(bf16x8*)(&Cout[(size_t)grow * N + gc]) = vv;
        }
    }
}

extern "C" void kernel_launch(void* const* d_in, const int* in_sizes, int n_in,
                              void* d_out, int out_size, void* d_ws, size_t ws_size,
                              hipStream_t stream) {
    const float* x        = (const float*)d_in[0];
    const int*   src      = (const int*)d_in[1];
    const int*   dst      = (const int*)d_in[2];
    const float* W_self1  = (const float*)d_in[3];
    const float* W_neigh1 = (const float*)d_in[4];
    const float* b1       = (const float*)d_in[5];
    const float* W_self2  = (const float*)d_in[6];
    const float* W_neigh2 = (const float*)d_in[7];
    const float* b2       = (const float*)d_in[8];
    float* out = (float*)d_out;

    // ---- workspace layout ----
    char* p = (char*)d_ws;
    auto alloc = [&](size_t bytes) { char* r = p; p += (bytes + 255) & ~(size_t)255; return r; };
    float*    invdeg   = (float*)alloc((size_t)N_NODES * 4);
    ushort_t* A1       = (ushort_t*)alloc((size_t)N_NODES * 256 * 2);  // [x | agg]
    ushort_t* h        = (ushort_t*)alloc((size_t)N_NODES * 256 * 2);
    ushort_t* u        = (ushort_t*)alloc((size_t)N_NODES * 256 * 2);  // [u_self | u_neigh]
    ushort_t* Wt1      = (ushort_t*)alloc((size_t)256 * 256 * 2);
    ushort_t* Wt2      = (ushort_t*)alloc((size_t)256 * 256 * 2);
    int* rowptr        = (int*)alloc((size_t)(N_NODES + 1) * 4);
    int* bucket_cnt    = (int*)alloc((size_t)NBUCK * 4);
    int* bbase         = (int*)alloc((size_t)(NBUCK + 1) * 4);
    int* bcursor       = (int*)alloc((size_t)NBUCK * 4);
    unsigned int* pairs= (unsigned int*)alloc((size_t)N_EDGES * 4);
    int* csr_src       = (int*)alloc((size_t)N_EDGES * 4);

    // ---- converts ----
    convert_x_kernel<<<(N_NODES * F_IN / 4 + 255) / 256, 256, 0, stream>>>(
        x, A1, N_NODES * F_IN / 4);
    wtransK_kernel<<<(256 * 256 + 255) / 256, 256, 0, stream>>>(
        W_self1, W_neigh1, Wt1, 128, 256, 256);
    wtransN_kernel<<<(256 * 256 + 255) / 256, 256, 0, stream>>>(
        W_self2, W_neigh2, Wt2, 256, 128);

    // ---- CSR build: bucket count -> scan -> bin -> sort(+rowptr+invdeg) ----
    hipMemsetAsync(bucket_cnt, 0, (size_t)NBUCK * sizeof(int), stream);
    bucket_count_kernel<<<(N_EDGES + CHUNK - 1) / CHUNK, 256, 0, stream>>>(
        dst, bucket_cnt, N_EDGES);
    bucket_scan_kernel<<<1, 512, 0, stream>>>(bucket_cnt, bbase, bcursor, rowptr);
    bin_edges_kernel<<<(N_EDGES + CHUNK - 1) / CHUNK, 256, 0, stream>>>(
        src, dst, bcursor, pairs, N_EDGES);
    sort_bucket_kernel<<<NBUCK, 256, 0, stream>>>(
        pairs, bbase, rowptr, invdeg, csr_src, N_NODES);

    // ---- layer 1: gather x -> A1[:,128:256], then h = sigmoid(A1 @ Wt1 + b1) ----
    gather16_kernel<0><<<(N_NODES + 3) / 4, 256, 0, stream>>>(
        A1, 256, rowptr, csr_src, invdeg, nullptr, 0, nullptr, A1 + 128, 256, N_NODES);
    {
        dim3 grid((N_NODES + 127) / 128, 2);
        gemm_mfma_kernel<<<grid, 256, 0, stream>>>(A1, Wt1, b1, h, N_NODES, 256, 256, 0);
    }

    // ---- layer 2: u = h @ [Ws2|Wn2] (one pass) ----
    {
        dim3 grid((N_NODES + 127) / 128, 2);
        gemm_mfma_kernel<<<grid, 256, 0, stream>>>(h, Wt2, nullptr, u, N_NODES, 256, 256, 1);
    }
    // ---- out = u_self + b2 + invdeg * gather(u_neigh) ----
    gather16_kernel<1><<<(N_NODES + 3) / 4, 256, 0, stream>>>(
        u + 128, 256, rowptr, csr_src, invdeg, u, 256, b2, out, 128, N_NODES);
}

// Round 12
// 292.489 us; speedup vs baseline: 1.5711x; 1.0539x over previous
//
#include <hip/hip_runtime.h>
#include <hip/hip_bf16.h>

#define N_NODES 100000
#define N_EDGES 1600000
#define F_IN 128
#define F_HID 256
#define F_OUT 128

typedef unsigned short ushort_t;
typedef __attribute__((ext_vector_type(4))) float f32x4;
typedef __attribute__((ext_vector_type(8))) short bf16x8;

#define GAS __attribute__((address_space(1)))
#define LAS __attribute__((address_space(3)))

__device__ __forceinline__ float bf2f(ushort_t u) {
    unsigned int x = ((unsigned int)u) << 16;
    return __builtin_bit_cast(float, x);
}
__device__ __forceinline__ ushort_t f2bf(float f) {
    unsigned int x = __builtin_bit_cast(unsigned int, f);
    unsigned int r = (x + 0x7fffu + ((x >> 16) & 1u)) >> 16;
    return (ushort_t)r;
}

// ---------------- bucket-sort CSR build (round-11, unchanged) ----------------
#define NBUCK ((N_NODES + 255) >> 8)  // 391
#define CHUNK 4096

__global__ __launch_bounds__(256) void bucket_count_kernel(
    const int* __restrict__ dst, int* __restrict__ bucket_cnt, int n) {
    __shared__ int hist[NBUCK];
    int tid = threadIdx.x;
    int e0 = blockIdx.x * CHUNK;
    int cnt = n - e0; if (cnt > CHUNK) cnt = CHUNK;
    for (int b = tid; b < NBUCK; b += 256) hist[b] = 0;
    __syncthreads();
    for (int i = tid; i < cnt; i += 256) {
        int d = __builtin_nontemporal_load(dst + e0 + i);
        atomicAdd(&hist[d >> 8], 1);
    }
    __syncthreads();
    for (int b = tid; b < NBUCK; b += 256)
        if (hist[b]) atomicAdd(&bucket_cnt[b], hist[b]);
}

__global__ __launch_bounds__(512) void bucket_scan_kernel(
    const int* __restrict__ bucket_cnt, int* __restrict__ bbase,
    int* __restrict__ bcursor, int* __restrict__ rowptr) {
    __shared__ int tmp[512];
    int tid = threadIdx.x;
    int v = (tid < NBUCK) ? bucket_cnt[tid] : 0;
    tmp[tid] = v;
    __syncthreads();
#pragma unroll
    for (int off = 1; off < 512; off <<= 1) {
        int t = (tid >= off) ? tmp[tid - off] : 0;
        __syncthreads();
        tmp[tid] += t;
        __syncthreads();
    }
    if (tid < NBUCK) {
        int base = tmp[tid] - v;
        bbase[tid] = base;
        bcursor[tid] = base;
    }
    if (tid == 0) {
        bbase[NBUCK] = N_EDGES;
        rowptr[N_NODES] = N_EDGES;
    }
}

__global__ __launch_bounds__(256) void bin_edges_kernel(
    const int* __restrict__ src, const int* __restrict__ dst,
    int* __restrict__ bcursor, unsigned int* __restrict__ pairs, int n) {
    __shared__ int sdst[CHUNK];
    __shared__ int ssrc[CHUNK];
    __shared__ int hist[NBUCK];
    __shared__ int resv[NBUCK];
    int tid = threadIdx.x;
    int e0 = blockIdx.x * CHUNK;
    int cnt = n - e0; if (cnt > CHUNK) cnt = CHUNK;
    for (int b = tid; b < NBUCK; b += 256) hist[b] = 0;
    __syncthreads();
    for (int i = tid; i < cnt; i += 256) {
        int d = __builtin_nontemporal_load(dst + e0 + i);
        int s = __builtin_nontemporal_load(src + e0 + i);
        sdst[i] = d;
        ssrc[i] = s;
        atomicAdd(&hist[d >> 8], 1);
    }
    __syncthreads();
    for (int b = tid; b < NBUCK; b += 256) {
        int h = hist[b];
        resv[b] = h ? atomicAdd(&bcursor[b], h) : 0;
        hist[b] = 0;
    }
    __syncthreads();
    for (int i = tid; i < cnt; i += 256) {
        int d = sdst[i], s = ssrc[i];
        int b = d >> 8;
        int off = atomicAdd(&hist[b], 1);
        pairs[resv[b] + off] = ((unsigned)(d & 255) << 17) | (unsigned)s;
    }
}

__global__ __launch_bounds__(256) void sort_bucket_kernel(
    const unsigned int* __restrict__ pairs, const int* __restrict__ bbase,
    int* __restrict__ rowptr, float* __restrict__ invdeg,
    int* __restrict__ csr_src, int nNodes) {
    __shared__ int lcnt[256];
    __shared__ int lrp[256];
    int tid = threadIdx.x;
    int base = blockIdx.x << 8;
    int nn = nNodes - base; if (nn > 256) nn = 256;
    lcnt[tid] = 0;
    __syncthreads();
    int e0 = bbase[blockIdx.x], e1 = bbase[blockIdx.x + 1];
    for (int i = e0 + tid; i < e1; i += 256)
        atomicAdd(&lcnt[pairs[i] >> 17], 1);
    __syncthreads();
    int v = lcnt[tid];
    lrp[tid] = v;
    __syncthreads();
#pragma unroll
    for (int off = 1; off < 256; off <<= 1) {
        int t = (tid >= off) ? lrp[tid - off] : 0;
        __syncthreads();
        lrp[tid] += t;
        __syncthreads();
    }
    lcnt[tid] = 0;
    lrp[tid] = lrp[tid] - v + e0;
    if (tid < nn) {
        rowptr[base + tid] = lrp[tid];
        invdeg[base + tid] = 1.0f / fmaxf((float)v, 1.0f);
    }
    __syncthreads();
    for (int i = e0 + tid; i < e1; i += 256) {
        unsigned pv = pairs[i];
        int j = (int)(pv >> 17);
        int off = atomicAdd(&lcnt[j], 1);
        csr_src[lrp[j] + off] = (int)(pv & 0x1FFFFu);
    }
}

// ---------------- fp32 -> bf16 converts ----------------
// x -> xb compact [N][128]
__global__ __launch_bounds__(256) void convert_x_kernel(const float* __restrict__ x,
                                                        ushort_t* __restrict__ xb, int n4) {
    int i = blockIdx.x * 256 + threadIdx.x;
    if (i >= n4) return;
    int e = i * 4;
    f32x4 v = __builtin_nontemporal_load((const f32x4*)(x + e));
    ushort4 o;
    o.x = f2bf(v.x); o.y = f2bf(v.y); o.z = f2bf(v.z); o.w = f2bf(v.w);
    *(ushort4*)(xb + e) = o;
}

__global__ __launch_bounds__(256) void wtransK_kernel(const float* __restrict__ W1,
                                                      const float* __restrict__ W2,
                                                      ushort_t* __restrict__ Wt,
                                                      int Kx, int Ktot, int N) {
    int i = blockIdx.x * 256 + threadIdx.x;
    if (i >= N * Ktot) return;
    int n = i / Ktot, k = i - n * Ktot;
    float v = (k < Kx) ? W1[(size_t)k * N + n] : W2[(size_t)(k - Kx) * N + n];
    Wt[(size_t)n * Ktot + k] = f2bf(v);
}

__global__ __launch_bounds__(256) void wtransN_kernel(const float* __restrict__ Wa,
                                                      const float* __restrict__ Wb,
                                                      ushort_t* __restrict__ Wt,
                                                      int K, int Nh) {
    int i = blockIdx.x * 256 + threadIdx.x;
    if (i >= 2 * Nh * K) return;
    int n = i / K, k = i - n * K;
    const float* W = (n < Nh) ? Wa : Wb;
    int nn = (n < Nh) ? n : n - Nh;
    Wt[(size_t)n * K + k] = f2bf(W[(size_t)k * Nh + nn]);
}

// ---------------- persistent dual-node gather ----------------
// One wave owns node pairs (grid-stride). 16 lanes per edge, 4 edge slots per
// node, TWO nodes in flight -> 8 H-row loads (2KB) outstanding. Next pair's
// rowptr values are prefetched before the current pair's accumulate (eA==sB,
// so 3 loads cover both nodes).
#define ACC8(arr, v)                                                \
    arr[0] += bf2f((ushort_t)((v).x & 0xffffu));                    \
    arr[1] += bf2f((ushort_t)((v).x >> 16));                        \
    arr[2] += bf2f((ushort_t)((v).y & 0xffffu));                    \
    arr[3] += bf2f((ushort_t)((v).y >> 16));                        \
    arr[4] += bf2f((ushort_t)((v).z & 0xffffu));                    \
    arr[5] += bf2f((ushort_t)((v).z >> 16));                        \
    arr[6] += bf2f((ushort_t)((v).w & 0xffffu));                    \
    arr[7] += bf2f((ushort_t)((v).w >> 16));

// MODE 0: out bf16 [N][128] = mean  ; MODE 1: out f32 [N][128] = uself+bias+mean
template <int MODE>
__global__ __launch_bounds__(256) void gather2_kernel(
    const ushort_t* __restrict__ H,       // [N][128] bf16
    const int* __restrict__ rowptr,
    const int* __restrict__ csr_src,
    const float* __restrict__ invdeg,
    const ushort_t* __restrict__ uself,   // [N][128] (MODE 1)
    const float* __restrict__ bias,       // (MODE 1)
    void* __restrict__ outp,
    int nNodes, int totWaves) {
    int lane = threadIdx.x & 63;
    int wv = blockIdx.x * 4 + (threadIdx.x >> 6);
    int grp = lane >> 4, sub = lane & 15;
    const size_t cofs = (size_t)sub * 8;
    int pair = wv;
    if (pair * 2 >= nNodes) return;
    int r0 = rowptr[pair * 2];
    int r1 = rowptr[pair * 2 + 1];
    int r2 = rowptr[pair * 2 + 2];
    while (true) {
        int npair = pair + totWaves;
        bool hasNext = (npair * 2 < nNodes);
        int n0 = 0, n1 = 0, n2 = 0;
        if (hasNext) {  // prefetch next pair's meta; latency hides under H loads
            n0 = rowptr[npair * 2];
            n1 = rowptr[npair * 2 + 1];
            n2 = rowptr[npair * 2 + 2];
        }
        int nodeA = pair * 2;
        int sA = r0, eA = r1, sB = r1, eB = r2;
        int cA = sA < N_EDGES ? sA : N_EDGES - 1;
        int cB = sB < N_EDGES ? sB : N_EDGES - 1;
        float accA[8] = {}, accB[8] = {};
        for (int ea = sA + grp, eb = sB + grp; ea < eA || eb < eB; ea += 16, eb += 16) {
            bool pa0 = ea < eA, pa1 = ea + 4 < eA, pa2 = ea + 8 < eA, pa3 = ea + 12 < eA;
            bool pb0 = eb < eB, pb1 = eb + 4 < eB, pb2 = eb + 8 < eB, pb3 = eb + 12 < eB;
            int ja0 = pa0 ? ea : cA, ja1 = pa1 ? ea + 4 : cA;
            int ja2 = pa2 ? ea + 8 : cA, ja3 = pa3 ? ea + 12 : cA;
            int jb0 = pb0 ? eb : cB, jb1 = pb1 ? eb + 4 : cB;
            int jb2 = pb2 ? eb + 8 : cB, jb3 = pb3 ? eb + 12 : cB;
            int sa0 = csr_src[ja0], sa1 = csr_src[ja1];
            int sa2 = csr_src[ja2], sa3 = csr_src[ja3];
            int sb0 = csr_src[jb0], sb1 = csr_src[jb1];
            int sb2 = csr_src[jb2], sb3 = csr_src[jb3];
            uint4 va0 = *(const uint4*)(H + (size_t)sa0 * 128 + cofs);
            uint4 va1 = *(const uint4*)(H + (size_t)sa1 * 128 + cofs);
            uint4 va2 = *(const uint4*)(H + (size_t)sa2 * 128 + cofs);
            uint4 va3 = *(const uint4*)(H + (size_t)sa3 * 128 + cofs);
            uint4 vb0 = *(const uint4*)(H + (size_t)sb0 * 128 + cofs);
            uint4 vb1 = *(const uint4*)(H + (size_t)sb1 * 128 + cofs);
            uint4 vb2 = *(const uint4*)(H + (size_t)sb2 * 128 + cofs);
            uint4 vb3 = *(const uint4*)(H + (size_t)sb3 * 128 + cofs);
            if (pa0) { ACC8(accA, va0); }
            if (pa1) { ACC8(accA, va1); }
            if (pa2) { ACC8(accA, va2); }
            if (pa3) { ACC8(accA, va3); }
            if (pb0) { ACC8(accB, vb0); }
            if (pb1) { ACC8(accB, vb1); }
            if (pb2) { ACC8(accB, vb2); }
            if (pb3) { ACC8(accB, vb3); }
        }
#pragma unroll
        for (int j = 0; j < 8; ++j) {
            accA[j] += __shfl_xor(accA[j], 16);
            accA[j] += __shfl_xor(accA[j], 32);
            accB[j] += __shfl_xor(accB[j], 16);
            accB[j] += __shfl_xor(accB[j], 32);
        }
        if (grp == 0) {
            int nodeB = nodeA + 1;
            float scA = invdeg[nodeA];
            float scB = (nodeB < nNodes) ? invdeg[nodeB] : 1.0f;
            if (MODE == 0) {
                uint4 o;
                o.x = (unsigned)f2bf(accA[0] * scA) | ((unsigned)f2bf(accA[1] * scA) << 16);
                o.y = (unsigned)f2bf(accA[2] * scA) | ((unsigned)f2bf(accA[3] * scA) << 16);
                o.z = (unsigned)f2bf(accA[4] * scA) | ((unsigned)f2bf(accA[5] * scA) << 16);
                o.w = (unsigned)f2bf(accA[6] * scA) | ((unsigned)f2bf(accA[7] * scA) << 16);
                *(uint4*)((ushort_t*)outp + (size_t)nodeA * 128 + cofs) = o;
                if (nodeB < nNodes) {
                    uint4 p2;
                    p2.x = (unsigned)f2bf(accB[0] * scB) | ((unsigned)f2bf(accB[1] * scB) << 16);
                    p2.y = (unsigned)f2bf(accB[2] * scB) | ((unsigned)f2bf(accB[3] * scB) << 16);
                    p2.z = (unsigned)f2bf(accB[4] * scB) | ((unsigned)f2bf(accB[5] * scB) << 16);
                    p2.w = (unsigned)f2bf(accB[6] * scB) | ((unsigned)f2bf(accB[7] * scB) << 16);
                    *(uint4*)((ushort_t*)outp + (size_t)nodeB * 128 + cofs) = p2;
                }
            } else {
                uint4 us = *(const uint4*)(uself + (size_t)nodeA * 128 + cofs);
                f32x4 o0, o1;
                o0.x = accA[0] * scA + bf2f((ushort_t)(us.x & 0xffffu)) + bias[cofs + 0];
                o0.y = accA[1] * scA + bf2f((ushort_t)(us.x >> 16)) + bias[cofs + 1];
                o0.z = accA[2] * scA + bf2f((ushort_t)(us.y & 0xffffu)) + bias[cofs + 2];
                o0.w = accA[3] * scA + bf2f((ushort_t)(us.y >> 16)) + bias[cofs + 3];
                o1.x = accA[4] * scA + bf2f((ushort_t)(us.z & 0xffffu)) + bias[cofs + 4];
                o1.y = accA[5] * scA + bf2f((ushort_t)(us.z >> 16)) + bias[cofs + 5];
                o1.z = accA[6] * scA + bf2f((ushort_t)(us.w & 0xffffu)) + bias[cofs + 6];
                o1.w = accA[7] * scA + bf2f((ushort_t)(us.w >> 16)) + bias[cofs + 7];
                float* op = (float*)outp + (size_t)nodeA * 128 + cofs;
                __builtin_nontemporal_store(o0, (f32x4*)op);
                __builtin_nontemporal_store(o1, (f32x4*)(op + 4));
                if (nodeB < nNodes) {
                    uint4 u2 = *(const uint4*)(uself + (size_t)nodeB * 128 + cofs);
                    f32x4 q0, q1;
                    q0.x = accB[0] * scB + bf2f((ushort_t)(u2.x & 0xffffu)) + bias[cofs + 0];
                    q0.y = accB[1] * scB + bf2f((ushort_t)(u2.x >> 16)) + bias[cofs + 1];
                    q0.z = accB[2] * scB + bf2f((ushort_t)(u2.y & 0xffffu)) + bias[cofs + 2];
                    q0.w = accB[3] * scB + bf2f((ushort_t)(u2.y >> 16)) + bias[cofs + 3];
                    q1.x = accB[4] * scB + bf2f((ushort_t)(u2.z & 0xffffu)) + bias[cofs + 4];
                    q1.y = accB[5] * scB + bf2f((ushort_t)(u2.z >> 16)) + bias[cofs + 5];
                    q1.z = accB[6] * scB + bf2f((ushort_t)(u2.w & 0xffffu)) + bias[cofs + 6];
                    q1.w = accB[7] * scB + bf2f((ushort_t)(u2.w >> 16)) + bias[cofs + 7];
                    float* oq = (float*)outp + (size_t)nodeB * 128 + cofs;
                    __builtin_nontemporal_store(q0, (f32x4*)oq);
                    __builtin_nontemporal_store(q1, (f32x4*)(oq + 4));
                }
            }
        }
        if (!hasNext) break;
        pair = npair; r0 = n0; r1 = n1; r2 = n2;
    }
}

// ---------------- bf16 MFMA GEMM (N=K=256 fixed, split-A, dual-out) --------
// C = A'[M][256] @ Bt[256][256]^T ; 128x128 tile, 4 waves.
// A' cols k<Kx from A1 (lda1), k>=Kx from A2 (lda2).
// Output col<128 -> CoutA (ldcA), col>=128 -> CoutB (ldcB).
// mode 0: +bias+sigmoid bf16 ; mode 1: bf16
__global__ __launch_bounds__(256) void gemm_mfma_kernel(
    const ushort_t* __restrict__ A1, int lda1,
    const ushort_t* __restrict__ A2, int lda2, int Kx,
    const ushort_t* __restrict__ Bt,
    const float* __restrict__ bias,
    ushort_t* __restrict__ CoutA, int ldcA,
    ushort_t* __restrict__ CoutB, int ldcB,
    int M, int mode) {
    __shared__ ushort_t shmem[2 * 128 * 64];
    ushort_t* As = shmem;
    ushort_t* Bs = shmem + 128 * 64;
    int tid = threadIdx.x;
    int lane = tid & 63, wid = tid >> 6;
    int l15 = lane & 15, kgrp = lane >> 4, l7 = lane & 7, l8 = lane >> 3;
    int bm = blockIdx.x * 128, bn = blockIdx.y * 128;
    int wr = (wid >> 1) * 64, wc = (wid & 1) * 64;

    f32x4 acc[4][4] = {};

    for (int k0 = 0; k0 < 256; k0 += 64) {
        const ushort_t* Ap = (k0 < Kx) ? A1 : A2;
        int lda = (k0 < Kx) ? lda1 : lda2;
        int kk0 = (k0 < Kx) ? k0 : k0 - Kx;
#pragma unroll
        for (int t = 0; t < 4; ++t) {
            int c = wid * 4 + t;
            int row = c * 8 + l8;
            int scol = ((l7 ^ (row & 7)) << 3);
            int ar = bm + row; if (ar > M - 1) ar = M - 1;
            __builtin_amdgcn_global_load_lds(
                (const GAS void*)(Ap + (size_t)ar * lda + kk0 + scol),
                (LAS void*)(&As[c * 512]), 16, 0, 0);
            int br = bn + row;
            __builtin_amdgcn_global_load_lds(
                (const GAS void*)(Bt + (size_t)br * 256 + k0 + scol),
                (LAS void*)(&Bs[c * 512]), 16, 0, 0);
        }
        __syncthreads();
#pragma unroll
        for (int kk = 0; kk < 2; ++kk) {
            bf16x8 af[4], bfv[4];
#pragma unroll
            for (int mi = 0; mi < 4; ++mi) {
                int row = wr + mi * 16 + l15;
                int kel = (kk * 32 + kgrp * 8) ^ ((row & 7) << 3);
                af[mi] = *(const bf16x8*)(&As[row * 64 + kel]);
            }
#pragma unroll
            for (int ni = 0; ni < 4; ++ni) {
                int row = wc + ni * 16 + l15;
                int kel = (kk * 32 + kgrp * 8) ^ ((row & 7) << 3);
                bfv[ni] = *(const bf16x8*)(&Bs[row * 64 + kel]);
            }
#pragma unroll
            for (int mi = 0; mi < 4; ++mi)
#pragma unroll
                for (int ni = 0; ni < 4; ++ni)
                    acc[mi][ni] = __builtin_amdgcn_mfma_f32_16x16x32_bf16(
                        af[mi], bfv[ni], acc[mi][ni], 0, 0, 0);
        }
        __syncthreads();
    }

    // epilogue: wave-local 64x64 LDS transpose -> 16B stores, dual-output
    ushort_t* my = shmem + wid * 4096;
#pragma unroll
    for (int mi = 0; mi < 4; ++mi) {
#pragma unroll
        for (int ni = 0; ni < 4; ++ni) {
            int gcol = bn + wc + ni * 16 + l15;
#pragma unroll
            for (int r = 0; r < 4; ++r) {
                float v = acc[mi][ni][r];
                if (mode == 0) {
                    v += bias[gcol];
                    v = 1.0f / (1.0f + __expf(-v));
                }
                int lr = mi * 16 + kgrp * 4 + r;
                int lc = (ni * 16 + l15) ^ (kgrp << 3);
                my[lr * 64 + lc] = f2bf(v);
            }
        }
    }
#pragma unroll
    for (int it = 0; it < 8; ++it) {
        int r2 = (lane >> 3) + it * 8;
        int swz = ((r2 >> 2) & 3) << 3;
        int c2 = ((lane & 7) << 3) ^ swz;
        bf16x8 vv = *(const bf16x8*)(&my[r2 * 64 + c2]);
        int grow = bm + wr + r2;
        if (grow < M) {
            int gc = bn + wc + (c2 ^ swz);
            ushort_t* dstp = (gc < 128)
                ? CoutA + (size_t)grow * ldcA + gc
                : CoutB + (size_t)grow * ldcB + (gc - 128);
            *(bf16x8*)dstp = vv;
        }
    }
}

extern "C" void kernel_launch(void* const* d_in, const int* in_sizes, int n_in,
                              void* d_out, int out_size, void* d_ws, size_t ws_size,
                              hipStream_t stream) {
    const float* x        = (const float*)d_in[0];
    const int*   src      = (const int*)d_in[1];
    const int*   dst      = (const int*)d_in[2];
    const float* W_self1  = (const float*)d_in[3];
    const float* W_neigh1 = (const float*)d_in[4];
    const float* b1       = (const float*)d_in[5];
    const float* W_self2  = (const float*)d_in[6];
    const float* W_neigh2 = (const float*)d_in[7];
    const float* b2       = (const float*)d_in[8];
    float* out = (float*)d_out;

    // ---- workspace layout ----
    char* p = (char*)d_ws;
    auto alloc = [&](size_t bytes) { char* r = p; p += (bytes + 255) & ~(size_t)255; return r; };
    float*    invdeg   = (float*)alloc((size_t)N_NODES * 4);
    ushort_t* xb       = (ushort_t*)alloc((size_t)N_NODES * 128 * 2);
    ushort_t* agg      = (ushort_t*)alloc((size_t)N_NODES * 128 * 2);
    ushort_t* h        = (ushort_t*)alloc((size_t)N_NODES * 256 * 2);
    ushort_t* uself    = (ushort_t*)alloc((size_t)N_NODES * 128 * 2);
    ushort_t* uneigh   = (ushort_t*)alloc((size_t)N_NODES * 128 * 2);
    ushort_t* Wt1      = (ushort_t*)alloc((size_t)256 * 256 * 2);
    ushort_t* Wt2      = (ushort_t*)alloc((size_t)256 * 256 * 2);
    int* rowptr        = (int*)alloc((size_t)(N_NODES + 1) * 4);
    int* bucket_cnt    = (int*)alloc((size_t)NBUCK * 4);
    int* bbase         = (int*)alloc((size_t)(NBUCK + 1) * 4);
    int* bcursor       = (int*)alloc((size_t)NBUCK * 4);
    unsigned int* pairs= (unsigned int*)alloc((size_t)N_EDGES * 4);
    int* csr_src       = (int*)alloc((size_t)N_EDGES * 4);

    // ---- converts ----
    convert_x_kernel<<<(N_NODES * F_IN / 4 + 255) / 256, 256, 0, stream>>>(
        x, xb, N_NODES * F_IN / 4);
    wtransK_kernel<<<(256 * 256 + 255) / 256, 256, 0, stream>>>(
        W_self1, W_neigh1, Wt1, 128, 256, 256);
    wtransN_kernel<<<(256 * 256 + 255) / 256, 256, 0, stream>>>(
        W_self2, W_neigh2, Wt2, 256, 128);

    // ---- CSR build ----
    hipMemsetAsync(bucket_cnt, 0, (size_t)NBUCK * sizeof(int), stream);
    bucket_count_kernel<<<(N_EDGES + CHUNK - 1) / CHUNK, 256, 0, stream>>>(
        dst, bucket_cnt, N_EDGES);
    bucket_scan_kernel<<<1, 512, 0, stream>>>(bucket_cnt, bbase, bcursor, rowptr);
    bin_edges_kernel<<<(N_EDGES + CHUNK - 1) / CHUNK, 256, 0, stream>>>(
        src, dst, bcursor, pairs, N_EDGES);
    sort_bucket_kernel<<<NBUCK, 256, 0, stream>>>(
        pairs, bbase, rowptr, invdeg, csr_src, N_NODES);

    const int GATHER_BLOCKS = 2048;
    const int TOT_WAVES = GATHER_BLOCKS * 4;

    // ---- layer 1: agg = mean-gather(xb); h = sigmoid([xb|agg] @ Wt1 + b1) ----
    gather2_kernel<0><<<GATHER_BLOCKS, 256, 0, stream>>>(
        xb, rowptr, csr_src, invdeg, nullptr, nullptr, agg, N_NODES, TOT_WAVES);
    {
        dim3 grid((N_NODES + 127) / 128, 2);
        gemm_mfma_kernel<<<grid, 256, 0, stream>>>(
            xb, 128, agg, 128, 128, Wt1, b1, h, 256, h + 128, 256, N_NODES, 0);
    }

    // ---- layer 2: [uself|uneigh] = h @ [Ws2|Wn2] (compact outputs) ----
    {
        dim3 grid((N_NODES + 127) / 128, 2);
        gemm_mfma_kernel<<<grid, 256, 0, stream>>>(
            h, 256, h, 256, 256, Wt2, nullptr, uself, 128, uneigh, 128, N_NODES, 1);
    }
    // ---- out = uself + b2 + invdeg * gather(uneigh) ----
    gather2_kernel<1><<<GATHER_BLOCKS, 256, 0, stream>>>(
        uneigh, rowptr, csr_src, invdeg, uself, b2, out, N_NODES, TOT_WAVES);
}

// Round 13
// 282.921 us; speedup vs baseline: 1.6242x; 1.0338x over previous
//
#include <hip/hip_runtime.h>
#include <hip/hip_bf16.h>

#define N_NODES 100000
#define N_EDGES 1600000
#define F_IN 128
#define F_HID 256
#define F_OUT 128

typedef unsigned short ushort_t;
typedef __attribute__((ext_vector_type(4))) float f32x4;
typedef __attribute__((ext_vector_type(8))) short bf16x8;

#define GAS __attribute__((address_space(1)))
#define LAS __attribute__((address_space(3)))

__device__ __forceinline__ float bf2f(ushort_t u) {
    unsigned int x = ((unsigned int)u) << 16;
    return __builtin_bit_cast(float, x);
}
__device__ __forceinline__ ushort_t f2bf(float f) {
    unsigned int x = __builtin_bit_cast(unsigned int, f);
    unsigned int r = (x + 0x7fffu + ((x >> 16) & 1u)) >> 16;
    return (ushort_t)r;
}

// ---------------- bucket-sort CSR build (round-11, unchanged) ----------------
#define NBUCK ((N_NODES + 255) >> 8)  // 391
#define CHUNK 4096

__global__ __launch_bounds__(256) void bucket_count_kernel(
    const int* __restrict__ dst, int* __restrict__ bucket_cnt, int n) {
    __shared__ int hist[NBUCK];
    int tid = threadIdx.x;
    int e0 = blockIdx.x * CHUNK;
    int cnt = n - e0; if (cnt > CHUNK) cnt = CHUNK;
    for (int b = tid; b < NBUCK; b += 256) hist[b] = 0;
    __syncthreads();
    for (int i = tid; i < cnt; i += 256) {
        int d = __builtin_nontemporal_load(dst + e0 + i);
        atomicAdd(&hist[d >> 8], 1);
    }
    __syncthreads();
    for (int b = tid; b < NBUCK; b += 256)
        if (hist[b]) atomicAdd(&bucket_cnt[b], hist[b]);
}

__global__ __launch_bounds__(512) void bucket_scan_kernel(
    const int* __restrict__ bucket_cnt, int* __restrict__ bbase,
    int* __restrict__ bcursor, int* __restrict__ rowptr) {
    __shared__ int tmp[512];
    int tid = threadIdx.x;
    int v = (tid < NBUCK) ? bucket_cnt[tid] : 0;
    tmp[tid] = v;
    __syncthreads();
#pragma unroll
    for (int off = 1; off < 512; off <<= 1) {
        int t = (tid >= off) ? tmp[tid - off] : 0;
        __syncthreads();
        tmp[tid] += t;
        __syncthreads();
    }
    if (tid < NBUCK) {
        int base = tmp[tid] - v;
        bbase[tid] = base;
        bcursor[tid] = base;
    }
    if (tid == 0) {
        bbase[NBUCK] = N_EDGES;
        rowptr[N_NODES] = N_EDGES;
    }
}

__global__ __launch_bounds__(256) void bin_edges_kernel(
    const int* __restrict__ src, const int* __restrict__ dst,
    int* __restrict__ bcursor, unsigned int* __restrict__ pairs, int n) {
    __shared__ int sdst[CHUNK];
    __shared__ int ssrc[CHUNK];
    __shared__ int hist[NBUCK];
    __shared__ int resv[NBUCK];
    int tid = threadIdx.x;
    int e0 = blockIdx.x * CHUNK;
    int cnt = n - e0; if (cnt > CHUNK) cnt = CHUNK;
    for (int b = tid; b < NBUCK; b += 256) hist[b] = 0;
    __syncthreads();
    for (int i = tid; i < cnt; i += 256) {
        int d = __builtin_nontemporal_load(dst + e0 + i);
        int s = __builtin_nontemporal_load(src + e0 + i);
        sdst[i] = d;
        ssrc[i] = s;
        atomicAdd(&hist[d >> 8], 1);
    }
    __syncthreads();
    for (int b = tid; b < NBUCK; b += 256) {
        int h = hist[b];
        resv[b] = h ? atomicAdd(&bcursor[b], h) : 0;
        hist[b] = 0;
    }
    __syncthreads();
    for (int i = tid; i < cnt; i += 256) {
        int d = sdst[i], s = ssrc[i];
        int b = d >> 8;
        int off = atomicAdd(&hist[b], 1);
        pairs[resv[b] + off] = ((unsigned)(d & 255) << 17) | (unsigned)s;
    }
}

__global__ __launch_bounds__(256) void sort_bucket_kernel(
    const unsigned int* __restrict__ pairs, const int* __restrict__ bbase,
    int* __restrict__ rowptr, float* __restrict__ invdeg,
    int* __restrict__ csr_src, int nNodes) {
    __shared__ int lcnt[256];
    __shared__ int lrp[256];
    int tid = threadIdx.x;
    int base = blockIdx.x << 8;
    int nn = nNodes - base; if (nn > 256) nn = 256;
    lcnt[tid] = 0;
    __syncthreads();
    int e0 = bbase[blockIdx.x], e1 = bbase[blockIdx.x + 1];
    for (int i = e0 + tid; i < e1; i += 256)
        atomicAdd(&lcnt[pairs[i] >> 17], 1);
    __syncthreads();
    int v = lcnt[tid];
    lrp[tid] = v;
    __syncthreads();
#pragma unroll
    for (int off = 1; off < 256; off <<= 1) {
        int t = (tid >= off) ? lrp[tid - off] : 0;
        __syncthreads();
        lrp[tid] += t;
        __syncthreads();
    }
    lcnt[tid] = 0;
    lrp[tid] = lrp[tid] - v + e0;
    if (tid < nn) {
        rowptr[base + tid] = lrp[tid];
        invdeg[base + tid] = 1.0f / fmaxf((float)v, 1.0f);
    }
    __syncthreads();
    for (int i = e0 + tid; i < e1; i += 256) {
        unsigned pv = pairs[i];
        int j = (int)(pv >> 17);
        int off = atomicAdd(&lcnt[j], 1);
        csr_src[lrp[j] + off] = (int)(pv & 0x1FFFFu);
    }
}

// ---------------- fp32 -> bf16 converts ----------------
__global__ __launch_bounds__(256) void convert_x_kernel(const float* __restrict__ x,
                                                        ushort_t* __restrict__ xb, int n4) {
    int i = blockIdx.x * 256 + threadIdx.x;
    if (i >= n4) return;
    int e = i * 4;
    f32x4 v = __builtin_nontemporal_load((const f32x4*)(x + e));
    ushort4 o;
    o.x = f2bf(v.x); o.y = f2bf(v.y); o.z = f2bf(v.z); o.w = f2bf(v.w);
    *(ushort4*)(xb + e) = o;
}

__global__ __launch_bounds__(256) void wtransK_kernel(const float* __restrict__ W1,
                                                      const float* __restrict__ W2,
                                                      ushort_t* __restrict__ Wt,
                                                      int Kx, int Ktot, int N) {
    int i = blockIdx.x * 256 + threadIdx.x;
    if (i >= N * Ktot) return;
    int n = i / Ktot, k = i - n * Ktot;
    float v = (k < Kx) ? W1[(size_t)k * N + n] : W2[(size_t)(k - Kx) * N + n];
    Wt[(size_t)n * Ktot + k] = f2bf(v);
}

__global__ __launch_bounds__(256) void wtransN_kernel(const float* __restrict__ Wa,
                                                      const float* __restrict__ Wb,
                                                      ushort_t* __restrict__ Wt,
                                                      int K, int Nh) {
    int i = blockIdx.x * 256 + threadIdx.x;
    if (i >= 2 * Nh * K) return;
    int n = i / K, k = i - n * K;
    const float* W = (n < Nh) ? Wa : Wb;
    int nn = (n < Nh) ? n : n - Nh;
    Wt[(size_t)n * K + k] = f2bf(W[(size_t)k * Nh + nn]);
}

// ---------------- persistent dual-node gather (round-12, unchanged) ---------
#define ACC8(arr, v)                                                \
    arr[0] += bf2f((ushort_t)((v).x & 0xffffu));                    \
    arr[1] += bf2f((ushort_t)((v).x >> 16));                        \
    arr[2] += bf2f((ushort_t)((v).y & 0xffffu));                    \
    arr[3] += bf2f((ushort_t)((v).y >> 16));                        \
    arr[4] += bf2f((ushort_t)((v).z & 0xffffu));                    \
    arr[5] += bf2f((ushort_t)((v).z >> 16));                        \
    arr[6] += bf2f((ushort_t)((v).w & 0xffffu));                    \
    arr[7] += bf2f((ushort_t)((v).w >> 16));

// MODE 0: out bf16 [N][128] = mean  ; MODE 1: out f32 [N][128] = uself+bias+mean
template <int MODE>
__global__ __launch_bounds__(256) void gather2_kernel(
    const ushort_t* __restrict__ H,
    const int* __restrict__ rowptr,
    const int* __restrict__ csr_src,
    const float* __restrict__ invdeg,
    const ushort_t* __restrict__ uself,
    const float* __restrict__ bias,
    void* __restrict__ outp,
    int nNodes, int totWaves) {
    int lane = threadIdx.x & 63;
    int wv = blockIdx.x * 4 + (threadIdx.x >> 6);
    int grp = lane >> 4, sub = lane & 15;
    const size_t cofs = (size_t)sub * 8;
    int pair = wv;
    if (pair * 2 >= nNodes) return;
    int r0 = rowptr[pair * 2];
    int r1 = rowptr[pair * 2 + 1];
    int r2 = rowptr[pair * 2 + 2];
    while (true) {
        int npair = pair + totWaves;
        bool hasNext = (npair * 2 < nNodes);
        int n0 = 0, n1 = 0, n2 = 0;
        if (hasNext) {
            n0 = rowptr[npair * 2];
            n1 = rowptr[npair * 2 + 1];
            n2 = rowptr[npair * 2 + 2];
        }
        int nodeA = pair * 2;
        int sA = r0, eA = r1, sB = r1, eB = r2;
        int cA = sA < N_EDGES ? sA : N_EDGES - 1;
        int cB = sB < N_EDGES ? sB : N_EDGES - 1;
        float accA[8] = {}, accB[8] = {};
        for (int ea = sA + grp, eb = sB + grp; ea < eA || eb < eB; ea += 16, eb += 16) {
            bool pa0 = ea < eA, pa1 = ea + 4 < eA, pa2 = ea + 8 < eA, pa3 = ea + 12 < eA;
            bool pb0 = eb < eB, pb1 = eb + 4 < eB, pb2 = eb + 8 < eB, pb3 = eb + 12 < eB;
            int ja0 = pa0 ? ea : cA, ja1 = pa1 ? ea + 4 : cA;
            int ja2 = pa2 ? ea + 8 : cA, ja3 = pa3 ? ea + 12 : cA;
            int jb0 = pb0 ? eb : cB, jb1 = pb1 ? eb + 4 : cB;
            int jb2 = pb2 ? eb + 8 : cB, jb3 = pb3 ? eb + 12 : cB;
            int sa0 = csr_src[ja0], sa1 = csr_src[ja1];
            int sa2 = csr_src[ja2], sa3 = csr_src[ja3];
            int sb0 = csr_src[jb0], sb1 = csr_src[jb1];
            int sb2 = csr_src[jb2], sb3 = csr_src[jb3];
            uint4 va0 = *(const uint4*)(H + (size_t)sa0 * 128 + cofs);
            uint4 va1 = *(const uint4*)(H + (size_t)sa1 * 128 + cofs);
            uint4 va2 = *(const uint4*)(H + (size_t)sa2 * 128 + cofs);
            uint4 va3 = *(const uint4*)(H + (size_t)sa3 * 128 + cofs);
            uint4 vb0 = *(const uint4*)(H + (size_t)sb0 * 128 + cofs);
            uint4 vb1 = *(const uint4*)(H + (size_t)sb1 * 128 + cofs);
            uint4 vb2 = *(const uint4*)(H + (size_t)sb2 * 128 + cofs);
            uint4 vb3 = *(const uint4*)(H + (size_t)sb3 * 128 + cofs);
            if (pa0) { ACC8(accA, va0); }
            if (pa1) { ACC8(accA, va1); }
            if (pa2) { ACC8(accA, va2); }
            if (pa3) { ACC8(accA, va3); }
            if (pb0) { ACC8(accB, vb0); }
            if (pb1) { ACC8(accB, vb1); }
            if (pb2) { ACC8(accB, vb2); }
            if (pb3) { ACC8(accB, vb3); }
        }
#pragma unroll
        for (int j = 0; j < 8; ++j) {
            accA[j] += __shfl_xor(accA[j], 16);
            accA[j] += __shfl_xor(accA[j], 32);
            accB[j] += __shfl_xor(accB[j], 16);
            accB[j] += __shfl_xor(accB[j], 32);
        }
        if (grp == 0) {
            int nodeB = nodeA + 1;
            float scA = invdeg[nodeA];
            float scB = (nodeB < nNodes) ? invdeg[nodeB] : 1.0f;
            if (MODE == 0) {
                uint4 o;
                o.x = (unsigned)f2bf(accA[0] * scA) | ((unsigned)f2bf(accA[1] * scA) << 16);
                o.y = (unsigned)f2bf(accA[2] * scA) | ((unsigned)f2bf(accA[3] * scA) << 16);
                o.z = (unsigned)f2bf(accA[4] * scA) | ((unsigned)f2bf(accA[5] * scA) << 16);
                o.w = (unsigned)f2bf(accA[6] * scA) | ((unsigned)f2bf(accA[7] * scA) << 16);
                *(uint4*)((ushort_t*)outp + (size_t)nodeA * 128 + cofs) = o;
                if (nodeB < nNodes) {
                    uint4 p2;
                    p2.x = (unsigned)f2bf(accB[0] * scB) | ((unsigned)f2bf(accB[1] * scB) << 16);
                    p2.y = (unsigned)f2bf(accB[2] * scB) | ((unsigned)f2bf(accB[3] * scB) << 16);
                    p2.z = (unsigned)f2bf(accB[4] * scB) | ((unsigned)f2bf(accB[5] * scB) << 16);
                    p2.w = (unsigned)f2bf(accB[6] * scB) | ((unsigned)f2bf(accB[7] * scB) << 16);
                    *(uint4*)((ushort_t*)outp + (size_t)nodeB * 128 + cofs) = p2;
                }
            } else {
                uint4 us = *(const uint4*)(uself + (size_t)nodeA * 128 + cofs);
                f32x4 o0, o1;
                o0.x = accA[0] * scA + bf2f((ushort_t)(us.x & 0xffffu)) + bias[cofs + 0];
                o0.y = accA[1] * scA + bf2f((ushort_t)(us.x >> 16)) + bias[cofs + 1];
                o0.z = accA[2] * scA + bf2f((ushort_t)(us.y & 0xffffu)) + bias[cofs + 2];
                o0.w = accA[3] * scA + bf2f((ushort_t)(us.y >> 16)) + bias[cofs + 3];
                o1.x = accA[4] * scA + bf2f((ushort_t)(us.z & 0xffffu)) + bias[cofs + 4];
                o1.y = accA[5] * scA + bf2f((ushort_t)(us.z >> 16)) + bias[cofs + 5];
                o1.z = accA[6] * scA + bf2f((ushort_t)(us.w & 0xffffu)) + bias[cofs + 6];
                o1.w = accA[7] * scA + bf2f((ushort_t)(us.w >> 16)) + bias[cofs + 7];
                float* op = (float*)outp + (size_t)nodeA * 128 + cofs;
                __builtin_nontemporal_store(o0, (f32x4*)op);
                __builtin_nontemporal_store(o1, (f32x4*)(op + 4));
                if (nodeB < nNodes) {
                    uint4 u2 = *(const uint4*)(uself + (size_t)nodeB * 128 + cofs);
                    f32x4 q0, q1;
                    q0.x = accB[0] * scB + bf2f((ushort_t)(u2.x & 0xffffu)) + bias[cofs + 0];
                    q0.y = accB[1] * scB + bf2f((ushort_t)(u2.x >> 16)) + bias[cofs + 1];
                    q0.z = accB[2] * scB + bf2f((ushort_t)(u2.y & 0xffffu)) + bias[cofs + 2];
                    q0.w = accB[3] * scB + bf2f((ushort_t)(u2.y >> 16)) + bias[cofs + 3];
                    q1.x = accB[4] * scB + bf2f((ushort_t)(u2.z & 0xffffu)) + bias[cofs + 4];
                    q1.y = accB[5] * scB + bf2f((ushort_t)(u2.z >> 16)) + bias[cofs + 5];
                    q1.z = accB[6] * scB + bf2f((ushort_t)(u2.w & 0xffffu)) + bias[cofs + 6];
                    q1.w = accB[7] * scB + bf2f((ushort_t)(u2.w >> 16)) + bias[cofs + 7];
                    float* oq = (float*)outp + (size_t)nodeB * 128 + cofs;
                    __builtin_nontemporal_store(q0, (f32x4*)oq);
                    __builtin_nontemporal_store(q1, (f32x4*)(oq + 4));
                }
            }
        }
        if (!hasNext) break;
        pair = npair; r0 = n0; r1 = n1; r2 = n2;
    }
}

// ---------------- 512-thread full-N double-buffered bf16 MFMA GEMM ----------
// C = A'[M][256] @ Bt[256][256]^T ; block = 128(M) x 256(N), 8 waves (2x4).
// BK=32, double-buffered: stage(next) issued BEFORE current step's MFMAs,
// ONE barrier per step -> staging overlaps compute (T3 2-phase minimum).
// A' cols k<Kx from A1(lda1), else A2(lda2). Output split at col 128.
// mode 0: +bias+sigmoid bf16 ; mode 1: bf16
__global__ __launch_bounds__(512) void gemm_mfma_kernel(
    const ushort_t* __restrict__ A1, int lda1,
    const ushort_t* __restrict__ A2, int lda2, int Kx,
    const ushort_t* __restrict__ Bt,
    const float* __restrict__ bias,
    ushort_t* __restrict__ CoutA, int ldcA,
    ushort_t* __restrict__ CoutB, int ldcB,
    int M, int mode) {
    __shared__ ushort_t shmem[2 * 128 * 32 + 2 * 256 * 32];  // 48KB
    ushort_t* Asb[2] = {shmem, shmem + 4096};
    ushort_t* Bsb[2] = {shmem + 8192, shmem + 16384};
    int tid = threadIdx.x;
    int lane = tid & 63, wid = tid >> 6;
    int l15 = lane & 15, kgrp = lane >> 4;
    int bm = blockIdx.x * 128;
    int wr = (wid >> 2) * 64, wc = (wid & 3) * 64;

    // stage K-step t into buffer buf. A: 8 chunks (1 per wave); B: 16 (2 per wave).
    // LDS dest is wave-uniform base; lane l writes bytes l*16 -> row c*16+(l>>2),
    // slot l&3. Source col slot inverse-swizzled by row&3 (rule 21).
    auto stage = [&](int buf, int t) {
        int k0 = t * 32;
        const ushort_t* Ap = (k0 < Kx) ? A1 : A2;
        int lda = (k0 < Kx) ? lda1 : lda2;
        int kk0 = (k0 < Kx) ? k0 : k0 - Kx;
        {
            int row = wid * 16 + (lane >> 2);
            int scol = ((lane & 3) ^ (row & 3)) << 3;
            int ar = bm + row; if (ar > M - 1) ar = M - 1;
            __builtin_amdgcn_global_load_lds(
                (const GAS void*)(Ap + (size_t)ar * lda + kk0 + scol),
                (LAS void*)(&Asb[buf][wid * 512]), 16, 0, 0);
        }
#pragma unroll
        for (int t2 = 0; t2 < 2; ++t2) {
            int c = wid * 2 + t2;
            int row = c * 16 + (lane >> 2);
            int scol = ((lane & 3) ^ (row & 3)) << 3;
            __builtin_amdgcn_global_load_lds(
                (const GAS void*)(Bt + (size_t)row * 256 + k0 + scol),
                (LAS void*)(&Bsb[buf][c * 512]), 16, 0, 0);
        }
    };

    f32x4 acc[4][4] = {};

    stage(0, 0);
    __syncthreads();  // prologue: buf0 ready
#pragma unroll
    for (int t = 0; t < 8; ++t) {
        int buf = t & 1;
        if (t < 7) stage(buf ^ 1, t + 1);  // in flight during MFMAs below
        bf16x8 af[4], bfv[4];
#pragma unroll
        for (int mi = 0; mi < 4; ++mi) {
            int row = wr + mi * 16 + l15;
            af[mi] = *(const bf16x8*)(&Asb[buf][row * 32 + ((kgrp ^ (row & 3)) << 3)]);
        }
#pragma unroll
        for (int ni = 0; ni < 4; ++ni) {
            int row = wc + ni * 16 + l15;
            bfv[ni] = *(const bf16x8*)(&Bsb[buf][row * 32 + ((kgrp ^ (row & 3)) << 3)]);
        }
#pragma unroll
        for (int mi = 0; mi < 4; ++mi)
#pragma unroll
            for (int ni = 0; ni < 4; ++ni)
                acc[mi][ni] = __builtin_amdgcn_mfma_f32_16x16x32_bf16(
                    af[mi], bfv[ni], acc[mi][ni], 0, 0, 0);
        __syncthreads();  // drains next-stage loads; protects buf reuse
    }

    // ---- epilogue: per-wave per-mi 16x64 transpose slabs (wave-private) ----
    ushort_t* my = shmem + wid * 1024;
#pragma unroll
    for (int mi = 0; mi < 4; ++mi) {
#pragma unroll
        for (int ni = 0; ni < 4; ++ni) {
            int gcol = wc + ni * 16 + l15;
#pragma unroll
            for (int r = 0; r < 4; ++r) {
                float v = acc[mi][ni][r];
                if (mode == 0) {
                    v += bias[gcol];
                    v = 1.0f / (1.0f + __expf(-v));
                }
                int lr = kgrp * 4 + r;
                int lc = (ni * 16 + l15) ^ (kgrp << 3);
                my[lr * 64 + lc] = f2bf(v);
            }
        }
#pragma unroll
        for (int it = 0; it < 2; ++it) {
            int r2 = (lane >> 3) + it * 8;
            int swz = ((r2 >> 2) & 3) << 3;
            int c2 = ((lane & 7) << 3) ^ swz;
            bf16x8 vv = *(const bf16x8*)(&my[r2 * 64 + c2]);
            int grow = bm + wr + mi * 16 + r2;
            if (grow < M) {
                int gc = wc + (c2 ^ swz);
                ushort_t* dstp = (gc < 128)
                    ? CoutA + (size_t)grow * ldcA + gc
                    : CoutB + (size_t)grow * ldcB + (gc - 128);
                *(bf16x8*)dstp = vv;
            }
        }
    }
}

extern "C" void kernel_launch(void* const* d_in, const int* in_sizes, int n_in,
                              void* d_out, int out_size, void* d_ws, size_t ws_size,
                              hipStream_t stream) {
    const float* x        = (const float*)d_in[0];
    const int*   src      = (const int*)d_in[1];
    const int*   dst      = (const int*)d_in[2];
    const float* W_self1  = (const float*)d_in[3];
    const float* W_neigh1 = (const float*)d_in[4];
    const float* b1       = (const float*)d_in[5];
    const float* W_self2  = (const float*)d_in[6];
    const float* W_neigh2 = (const float*)d_in[7];
    const float* b2       = (const float*)d_in[8];
    float* out = (float*)d_out;

    // ---- workspace layout ----
    char* p = (char*)d_ws;
    auto alloc = [&](size_t bytes) { char* r = p; p += (bytes + 255) & ~(size_t)255; return r; };
    float*    invdeg   = (float*)alloc((size_t)N_NODES * 4);
    ushort_t* xb       = (ushort_t*)alloc((size_t)N_NODES * 128 * 2);
    ushort_t* agg      = (ushort_t*)alloc((size_t)N_NODES * 128 * 2);
    ushort_t* h        = (ushort_t*)alloc((size_t)N_NODES * 256 * 2);
    ushort_t* uself    = (ushort_t*)alloc((size_t)N_NODES * 128 * 2);
    ushort_t* uneigh   = (ushort_t*)alloc((size_t)N_NODES * 128 * 2);
    ushort_t* Wt1      = (ushort_t*)alloc((size_t)256 * 256 * 2);
    ushort_t* Wt2      = (ushort_t*)alloc((size_t)256 * 256 * 2);
    int* rowptr        = (int*)alloc((size_t)(N_NODES + 1) * 4);
    int* bucket_cnt    = (int*)alloc((size_t)NBUCK * 4);
    int* bbase         = (int*)alloc((size_t)(NBUCK + 1) * 4);
    int* bcursor       = (int*)alloc((size_t)NBUCK * 4);
    unsigned int* pairs= (unsigned int*)alloc((size_t)N_EDGES * 4);
    int* csr_src       = (int*)alloc((size_t)N_EDGES * 4);

    // ---- converts ----
    convert_x_kernel<<<(N_NODES * F_IN / 4 + 255) / 256, 256, 0, stream>>>(
        x, xb, N_NODES * F_IN / 4);
    wtransK_kernel<<<(256 * 256 + 255) / 256, 256, 0, stream>>>(
        W_self1, W_neigh1, Wt1, 128, 256, 256);
    wtransN_kernel<<<(256 * 256 + 255) / 256, 256, 0, stream>>>(
        W_self2, W_neigh2, Wt2, 256, 128);

    // ---- CSR build ----
    hipMemsetAsync(bucket_cnt, 0, (size_t)NBUCK * sizeof(int), stream);
    bucket_count_kernel<<<(N_EDGES + CHUNK - 1) / CHUNK, 256, 0, stream>>>(
        dst, bucket_cnt, N_EDGES);
    bucket_scan_kernel<<<1, 512, 0, stream>>>(bucket_cnt, bbase, bcursor, rowptr);
    bin_edges_kernel<<<(N_EDGES + CHUNK - 1) / CHUNK, 256, 0, stream>>>(
        src, dst, bcursor, pairs, N_EDGES);
    sort_bucket_kernel<<<NBUCK, 256, 0, stream>>>(
        pairs, bbase, rowptr, invdeg, csr_src, N_NODES);

    const int GATHER_BLOCKS = 2048;
    const int TOT_WAVES = GATHER_BLOCKS * 4;

    // ---- layer 1: agg = mean-gather(xb); h = sigmoid([xb|agg] @ Wt1 + b1) ----
    gather2_kernel<0><<<GATHER_BLOCKS, 256, 0, stream>>>(
        xb, rowptr, csr_src, invdeg, nullptr, nullptr, agg, N_NODES, TOT_WAVES);
    {
        dim3 grid((N_NODES + 127) / 128);
        gemm_mfma_kernel<<<grid, 512, 0, stream>>>(
            xb, 128, agg, 128, 128, Wt1, b1, h, 256, h + 128, 256, N_NODES, 0);
    }

    // ---- layer 2: [uself|uneigh] = h @ [Ws2|Wn2] (compact outputs) ----
    {
        dim3 grid((N_NODES + 127) / 128);
        gemm_mfma_kernel<<<grid, 512, 0, stream>>>(
            h, 256, h, 256, 256, Wt2, nullptr, uself, 128, uneigh, 128, N_NODES, 1);
    }
    // ---- out = uself + b2 + invdeg * gather(uneigh) ----
    gather2_kernel<1><<<GATHER_BLOCKS, 256, 0, stream>>>(
        uneigh, rowptr, csr_src, invdeg, uself, b2, out, N_NODES, TOT_WAVES);
}